// Round 1
// baseline (300.931 us; speedup 1.0000x reference)
//
#include <hip/hip_runtime.h>
#include <cstdint>

// Address-space cast helpers for global_load_lds (C-style casts allowed for AS change)
#define AS1C(p) ((const __attribute__((address_space(1))) void*)(p))
#define AS3(p)  ((__attribute__((address_space(3))) void*)(p))

typedef __bf16 bf16x8 __attribute__((ext_vector_type(8)));
typedef float  f32x4  __attribute__((ext_vector_type(4)));

constexpr int B_ = 32, T_ = 512, D_ = 512, E_ = 8, H_ = 2048;

// ---------------- f32 -> bf16 convert (4 elems/thread) ----------------
__global__ void cvt_bf16_kernel(const float* __restrict__ in, __bf16* __restrict__ out, int n4) {
  int i = blockIdx.x * blockDim.x + threadIdx.x;
  if (i >= n4) return;
  float4 v = reinterpret_cast<const float4*>(in)[i];
  union { ushort4 u; __bf16 h[4]; } o;
  o.h[0] = (__bf16)v.x; o.h[1] = (__bf16)v.y; o.h[2] = (__bf16)v.z; o.h[3] = (__bf16)v.w;
  reinterpret_cast<ushort4*>(out)[i] = o.u;
}

// ---------------- tiled transpose + convert: src[R,C] f32 -> dst[C,R] bf16, per blockIdx.z slab ----
__global__ void transpose_cvt_kernel(const float* __restrict__ src, __bf16* __restrict__ dst,
                                     int R, int C) {
  __shared__ float tile[32][33];
  const float* s = src + (size_t)blockIdx.z * R * C;
  __bf16*      d = dst + (size_t)blockIdx.z * R * C;
  int c0 = blockIdx.x * 32, r0 = blockIdx.y * 32;
  int tx = threadIdx.x, ty = threadIdx.y;
#pragma unroll
  for (int i = 0; i < 4; ++i)
    tile[ty + i * 8][tx] = s[(size_t)(r0 + ty + i * 8) * C + c0 + tx];
  __syncthreads();
#pragma unroll
  for (int i = 0; i < 4; ++i)
    d[(size_t)(c0 + ty + i * 8) * R + r0 + tx] = (__bf16)tile[tx][ty + i * 8];
}

// ---------------- router: pooled mean -> softmax -> argmax ----------------
__global__ void router_kernel(const float* __restrict__ x, const float* __restrict__ Wp,
                              const float* __restrict__ bp, float* __restrict__ probs_out,
                              float* __restrict__ chosen_out_f, int* __restrict__ chosen_ws) {
  int b = blockIdx.x;
  int tid = threadIdx.x;  // 512 threads, one per d
  __shared__ float pooled[D_];
  __shared__ float part[E_][64];
  __shared__ float logits[E_];
  const float* xb = x + (size_t)b * T_ * D_;
  float s = 0.f;
  for (int t = 0; t < T_; ++t) s += xb[(size_t)t * D_ + tid];
  pooled[tid] = s * (1.0f / (float)T_);
  __syncthreads();
  int e = tid >> 6, dl = tid & 63;
  float p = 0.f;
  for (int d = dl; d < D_; d += 64) p += pooled[d] * Wp[d * E_ + e];
  part[e][dl] = p;
  __syncthreads();
  if (tid < E_) {
    float sum = bp[tid];
#pragma unroll
    for (int i = 0; i < 64; ++i) sum += part[tid][i];
    logits[tid] = sum;
  }
  __syncthreads();
  if (tid == 0) {
    float mx = logits[0]; int arg = 0;
    for (int i = 1; i < E_; ++i) if (logits[i] > mx) { mx = logits[i]; arg = i; }
    float ex[E_], se = 0.f;
    for (int i = 0; i < E_; ++i) { ex[i] = expf(logits[i] - mx); se += ex[i]; }
    float inv = 1.0f / se;
    for (int i = 0; i < E_; ++i) probs_out[b * E_ + i] = ex[i] * inv;
    chosen_out_f[b] = (float)arg;
    chosen_ws[b] = arg;
  }
}

// ---------------- batched GEMM, B^T input (m97-style 128x128/BK32) ----------------
// C[b] = epilogue(A[b] @ B[e]^T-view + bias[e]); A:[512,K] k-contig, BT:[N,K] k-contig.
template <int K, int N, bool RELU, typename OutT>
__global__ __launch_bounds__(256)
void gemm_bt_kernel(const __bf16* __restrict__ Aall, const __bf16* __restrict__ BTall,
                    const float* __restrict__ biasAll, OutT* __restrict__ Call,
                    const int* __restrict__ chosen) {
  const int b = blockIdx.z;
  const int e = chosen[b];
  const __bf16* A  = Aall  + (size_t)b * 512 * K;
  const __bf16* BT = BTall + (size_t)e * N * K;
  const float* bias = biasAll + (size_t)e * N;
  OutT* C = Call + (size_t)b * 512 * N;
  const int m0 = blockIdx.y * 128;
  const int n0 = blockIdx.x * 128;

  __shared__ __bf16 As[128 * 32];  // [m][k]
  __shared__ __bf16 Bs[128 * 32];  // [n][k]

  const int tid  = threadIdx.x;
  const int lane = tid & 63;
  const int w    = tid >> 6;
  const int wm = w >> 1, wn = w & 1;
  const int l16  = lane & 15;
  const int quad = lane >> 4;

  f32x4 acc[4][4] = {};

  for (int k0 = 0; k0 < K; k0 += 32) {
    // stage 8KB A-tile + 8KB B-tile; per wave: 2 insts each, 1KB per inst (lane*16B)
#pragma unroll
    for (int j = 0; j < 2; ++j) {
      const int f = w * 1024 + j * 512 + lane * 8;   // bf16 flat index within tile
      const int r = f >> 5, c = f & 31;
      __builtin_amdgcn_global_load_lds(AS1C(A + (size_t)(m0 + r) * K + k0 + c),
                                       AS3(As + w * 1024 + j * 512), 16, 0, 0);
      __builtin_amdgcn_global_load_lds(AS1C(BT + (size_t)(n0 + r) * K + k0 + c),
                                       AS3(Bs + w * 1024 + j * 512), 16, 0, 0);
    }
    asm volatile("s_waitcnt vmcnt(0)" ::: "memory");
    __syncthreads();
    bf16x8 af[4], bfr[4];
#pragma unroll
    for (int i = 0; i < 4; ++i) {
      af[i]  = *reinterpret_cast<const bf16x8*>(&As[(wm * 64 + i * 16 + l16) * 32 + quad * 8]);
      bfr[i] = *reinterpret_cast<const bf16x8*>(&Bs[(wn * 64 + i * 16 + l16) * 32 + quad * 8]);
    }
#pragma unroll
    for (int i = 0; i < 4; ++i)
#pragma unroll
      for (int jn = 0; jn < 4; ++jn)
        acc[i][jn] = __builtin_amdgcn_mfma_f32_16x16x32_bf16(af[i], bfr[jn], acc[i][jn], 0, 0, 0);
    __syncthreads();
  }

  // epilogue: C/D layout col=lane&15, row=quad*4+reg
#pragma unroll
  for (int jn = 0; jn < 4; ++jn) {
    const int gn = n0 + wn * 64 + jn * 16 + l16;
    const float bv = bias[gn];
#pragma unroll
    for (int i = 0; i < 4; ++i) {
#pragma unroll
      for (int r = 0; r < 4; ++r) {
        const int gm = m0 + wm * 64 + i * 16 + quad * 4 + r;
        float v = acc[i][jn][r] + bv;
        if (RELU) v = fmaxf(v, 0.f);
        C[(size_t)gm * N + gn] = (OutT)v;
      }
    }
  }
}

extern "C" void kernel_launch(void* const* d_in, const int* in_sizes, int n_in,
                              void* d_out, int out_size, void* d_ws, size_t ws_size,
                              hipStream_t stream) {
  const float* x  = (const float*)d_in[0];
  const float* Wp = (const float*)d_in[1];
  const float* bp = (const float*)d_in[2];
  const float* W1 = (const float*)d_in[3];
  const float* b1 = (const float*)d_in[4];
  const float* W2 = (const float*)d_in[5];
  const float* b2 = (const float*)d_in[6];
  float* out = (float*)d_out;

  // workspace layout (bytes): [0,128) chosen int32; bf16 buffers 256-aligned
  char* ws = (char*)d_ws;
  int*    chosen = (int*)ws;
  __bf16* xbf  = (__bf16*)(ws + 256);                                   // 16 MB
  __bf16* w1t  = (__bf16*)(ws + 256 + (size_t)16777216);                // 16 MB  [E,H,D]
  __bf16* w2t  = (__bf16*)(ws + 256 + (size_t)2 * 16777216);            // 16 MB  [E,D,H]
  __bf16* hbuf = (__bf16*)(ws + 256 + (size_t)3 * 16777216);            // 64 MB  [B,T,H]

  float* final_out  = out;                                // [B,T,D]
  float* probs_out  = out + (size_t)B_ * T_ * D_;         // [B,E]
  float* chosen_out = probs_out + B_ * E_;                // [B,1] as float

  router_kernel<<<B_, 512, 0, stream>>>(x, Wp, bp, probs_out, chosen_out, chosen);

  cvt_bf16_kernel<<<(B_ * T_ * D_ / 4 + 255) / 256, 256, 0, stream>>>(x, xbf, B_ * T_ * D_ / 4);
  // W1 [E,D,H] -> w1t [E,H,D]
  transpose_cvt_kernel<<<dim3(H_ / 32, D_ / 32, E_), dim3(32, 8), 0, stream>>>(W1, w1t, D_, H_);
  // W2 [E,H,D] -> w2t [E,D,H]
  transpose_cvt_kernel<<<dim3(D_ / 32, H_ / 32, E_), dim3(32, 8), 0, stream>>>(W2, w2t, H_, D_);

  // h = relu(x @ W1[e] + b1[e])  : M=512,K=512,N=2048, bf16 out
  gemm_bt_kernel<512, 2048, true, __bf16>
      <<<dim3(16, 4, 32), 256, 0, stream>>>(xbf, w1t, b1, hbuf, chosen);
  // out = h @ W2[e] + b2[e]      : M=512,K=2048,N=512, f32 out
  gemm_bt_kernel<2048, 512, false, float>
      <<<dim3(4, 4, 32), 256, 0, stream>>>(hbuf, w2t, b2, final_out, chosen);
}

// Round 2
// 266.067 us; speedup vs baseline: 1.1310x; 1.1310x over previous
//
#include <hip/hip_runtime.h>
#include <cstdint>

#define AS1C(p) ((const __attribute__((address_space(1))) void*)(p))
#define AS3(p)  ((__attribute__((address_space(3))) void*)(p))

typedef __bf16 bf16x8 __attribute__((ext_vector_type(8)));
typedef __bf16 bf16x2 __attribute__((ext_vector_type(2)));
typedef float  f32x4  __attribute__((ext_vector_type(4)));

constexpr int B_ = 32, T_ = 512, D_ = 512, E_ = 8, H_ = 2048;
constexpr int S_ = 16;  // mean-pool split factor

// ---------------- fused x -> bf16 convert + partial mean-pool ----------------
// grid (B, S), 256 threads; each block handles T/S=32 rows of one utterance.
__global__ __launch_bounds__(256)
void pool_cvt_kernel(const float* __restrict__ x, __bf16* __restrict__ xbf,
                     float* __restrict__ partial /*[B][S][D]*/) {
  const int b = blockIdx.x, s = blockIdx.y;
  const int tid = threadIdx.x;
  const size_t base = (size_t)b * T_ * D_ + (size_t)s * (T_ / S_) * D_;
  const float* xb = x + base;
  __bf16* ob = xbf + base;
  const int d0 = tid * 2;
  float s0 = 0.f, s1 = 0.f;
#pragma unroll
  for (int t = 0; t < T_ / S_; ++t) {
    float2 v = *reinterpret_cast<const float2*>(&xb[t * D_ + d0]);
    s0 += v.x; s1 += v.y;
    bf16x2 h; h[0] = (__bf16)v.x; h[1] = (__bf16)v.y;
    *reinterpret_cast<bf16x2*>(&ob[t * D_ + d0]) = h;
  }
  float* p = partial + ((size_t)b * S_ + s) * D_;
  p[d0] = s0; p[d0 + 1] = s1;
}

// ---------------- router finisher: reduce partials -> softmax -> argmax ----------------
__global__ void router2_kernel(const float* __restrict__ partial, const float* __restrict__ Wp,
                               const float* __restrict__ bp, float* __restrict__ probs_out,
                               float* __restrict__ chosen_out_f, int* __restrict__ chosen_ws) {
  const int b = blockIdx.x;
  const int tid = threadIdx.x;  // 512 threads, one per d
  __shared__ float pooled[D_];
  __shared__ float part[E_][64];
  __shared__ float logits[E_];
  const float* p = partial + (size_t)b * S_ * D_;
  float s = 0.f;
#pragma unroll
  for (int i = 0; i < S_; ++i) s += p[i * D_ + tid];
  pooled[tid] = s * (1.0f / (float)T_);
  __syncthreads();
  const int e = tid >> 6, dl = tid & 63;
  float acc = 0.f;
  for (int d = dl; d < D_; d += 64) acc += pooled[d] * Wp[d * E_ + e];
  part[e][dl] = acc;
  __syncthreads();
  if (tid < E_) {
    float sum = bp[tid];
#pragma unroll
    for (int i = 0; i < 64; ++i) sum += part[tid][i];
    logits[tid] = sum;
  }
  __syncthreads();
  if (tid == 0) {
    float mx = logits[0]; int arg = 0;
    for (int i = 1; i < E_; ++i) if (logits[i] > mx) { mx = logits[i]; arg = i; }
    float ex[E_], se = 0.f;
    for (int i = 0; i < E_; ++i) { ex[i] = expf(logits[i] - mx); se += ex[i]; }
    const float inv = 1.0f / se;
    for (int i = 0; i < E_; ++i) probs_out[b * E_ + i] = ex[i] * inv;
    chosen_out_f[b] = (float)arg;
    chosen_ws[b] = arg;
  }
}

// ---------------- merged transpose+convert for W1 and W2 ----------------
// 64x64 tiles; z<8 -> W1 slab e=z ([D,H] -> [H,D]); z>=8 -> W2 slab e=z-8 ([H,D] -> [D,H]).
__global__ __launch_bounds__(256)
void transpose_cvt2_kernel(const float* __restrict__ W1, const float* __restrict__ W2,
                           __bf16* __restrict__ w1t, __bf16* __restrict__ w2t) {
  const int z = blockIdx.z;
  const float* src; __bf16* dst; int R, C;
  if (z < E_) { src = W1 + (size_t)z * D_ * H_; dst = w1t + (size_t)z * D_ * H_; R = D_; C = H_; }
  else        { src = W2 + (size_t)(z - E_) * H_ * D_; dst = w2t + (size_t)(z - E_) * H_ * D_; R = H_; C = D_; }
  const int nTc = C >> 6;
  const int c0 = (blockIdx.x % nTc) * 64;
  const int r0 = (blockIdx.x / nTc) * 64;
  __shared__ float t[64][65];
  const int tid = threadIdx.x;
  const int lx = tid & 15, ly = tid >> 4;
#pragma unroll
  for (int i = 0; i < 4; ++i) {
    const int r = ly + i * 16;
    float4 v = *reinterpret_cast<const float4*>(&src[(size_t)(r0 + r) * C + c0 + lx * 4]);
    t[r][lx * 4 + 0] = v.x; t[r][lx * 4 + 1] = v.y;
    t[r][lx * 4 + 2] = v.z; t[r][lx * 4 + 3] = v.w;
  }
  __syncthreads();
#pragma unroll
  for (int h = 0; h < 2; ++h) {
    const int chunk = tid + h * 256;
    const int cc = chunk >> 3;          // output row (src col)
    const int rr = (chunk & 7) * 8;     // output col base (src row)
    bf16x8 o;
#pragma unroll
    for (int j = 0; j < 8; ++j) o[j] = (__bf16)t[rr + j][cc];
    *reinterpret_cast<bf16x8*>(&dst[(size_t)(c0 + cc) * R + r0 + rr]) = o;
  }
}

// ---------------- batched GEMM, B^T input, 128x128/BK32, XOR-swizzled LDS ----------------
// C[b] = epilogue(A[b] @ BT[e]^T + bias[e]); A:[512,K] k-contig, BT:[N,K] k-contig.
// LDS layout: tile row r's 4 khalf (16B) slots are permuted by slot q holding khalf q^((r>>1)&3):
// staging picks src col accordingly; fragment read uses quad^((l16>>1)&3) -> 2-way banks (free).
template <int K, int N, bool RELU, typename OutT>
__global__ __launch_bounds__(256)
void gemm_bt_kernel(const __bf16* __restrict__ Aall, const __bf16* __restrict__ BTall,
                    const float* __restrict__ biasAll, OutT* __restrict__ Call,
                    const int* __restrict__ chosen) {
  const int b = blockIdx.z;
  const int e = chosen[b];
  const __bf16* A  = Aall  + (size_t)b * 512 * K;
  const __bf16* BT = BTall + (size_t)e * N * K;
  const float* bias = biasAll + (size_t)e * N;
  OutT* C = Call + (size_t)b * 512 * N;
  const int m0 = blockIdx.y * 128;
  const int n0 = blockIdx.x * 128;

  __shared__ __bf16 As[128 * 32];  // [m][khalf-slot]
  __shared__ __bf16 Bs[128 * 32];  // [n][khalf-slot]

  const int tid  = threadIdx.x;
  const int lane = tid & 63;
  const int w    = tid >> 6;
  const int wm = w >> 1, wn = w & 1;
  const int l16  = lane & 15;
  const int quad = lane >> 4;
  const int sw   = (l16 >> 1) & 3;           // read-side swizzle
  const int qe   = (quad ^ sw) * 8;

  f32x4 acc[4][4] = {};

  for (int k0 = 0; k0 < K; k0 += 32) {
#pragma unroll
    for (int j = 0; j < 2; ++j) {
      const int f = w * 1024 + j * 512 + lane * 8;  // bf16 flat index within tile
      const int r = f >> 5;
      const int qs = (lane & 3) ^ ((r >> 1) & 3);   // swizzled source khalf
      __builtin_amdgcn_global_load_lds(AS1C(A + (size_t)(m0 + r) * K + k0 + qs * 8),
                                       AS3(As + w * 1024 + j * 512), 16, 0, 0);
      __builtin_amdgcn_global_load_lds(AS1C(BT + (size_t)(n0 + r) * K + k0 + qs * 8),
                                       AS3(Bs + w * 1024 + j * 512), 16, 0, 0);
    }
    asm volatile("s_waitcnt vmcnt(0)" ::: "memory");
    __syncthreads();
    bf16x8 af[4], bfr[4];
#pragma unroll
    for (int i = 0; i < 4; ++i) {
      af[i]  = *reinterpret_cast<const bf16x8*>(&As[(wm * 64 + i * 16 + l16) * 32 + qe]);
      bfr[i] = *reinterpret_cast<const bf16x8*>(&Bs[(wn * 64 + i * 16 + l16) * 32 + qe]);
    }
#pragma unroll
    for (int i = 0; i < 4; ++i)
#pragma unroll
      for (int jn = 0; jn < 4; ++jn)
        acc[i][jn] = __builtin_amdgcn_mfma_f32_16x16x32_bf16(af[i], bfr[jn], acc[i][jn], 0, 0, 0);
    __syncthreads();
  }

  // epilogue: C/D layout col=lane&15, row=quad*4+reg
#pragma unroll
  for (int jn = 0; jn < 4; ++jn) {
    const int gn = n0 + wn * 64 + jn * 16 + l16;
    const float bv = bias[gn];
#pragma unroll
    for (int i = 0; i < 4; ++i) {
#pragma unroll
      for (int r = 0; r < 4; ++r) {
        const int gm = m0 + wm * 64 + i * 16 + quad * 4 + r;
        float v = acc[i][jn][r] + bv;
        if (RELU) v = fmaxf(v, 0.f);
        C[(size_t)gm * N + gn] = (OutT)v;
      }
    }
  }
}

extern "C" void kernel_launch(void* const* d_in, const int* in_sizes, int n_in,
                              void* d_out, int out_size, void* d_ws, size_t ws_size,
                              hipStream_t stream) {
  const float* x  = (const float*)d_in[0];
  const float* Wp = (const float*)d_in[1];
  const float* bp = (const float*)d_in[2];
  const float* W1 = (const float*)d_in[3];
  const float* b1 = (const float*)d_in[4];
  const float* W2 = (const float*)d_in[5];
  const float* b2 = (const float*)d_in[6];
  float* out = (float*)d_out;

  // workspace layout (bytes): [0,256) chosen int32; bf16 buffers 256-aligned
  char* ws = (char*)d_ws;
  int*    chosen = (int*)ws;
  __bf16* xbf  = (__bf16*)(ws + 256);                          // 16 MB
  __bf16* w1t  = (__bf16*)(ws + 256 + (size_t)16777216);       // 16 MB  [E,H,D]
  __bf16* w2t  = (__bf16*)(ws + 256 + (size_t)2 * 16777216);   // 16 MB  [E,D,H]
  __bf16* hbuf = (__bf16*)(ws + 256 + (size_t)3 * 16777216);   // 64 MB  [B,T,H]

  float* final_out  = out;                                // [B,T,D]
  float* probs_out  = out + (size_t)B_ * T_ * D_;         // [B,E]
  float* chosen_out = probs_out + B_ * E_;                // [B,1] as float
  // partial pool sums live in the final_out region (consumed by router2 before gemm2 writes it)
  float* partial = out;                                   // [B][S][D] = 1 MB

  pool_cvt_kernel<<<dim3(B_, S_), 256, 0, stream>>>(x, xbf, partial);
  router2_kernel<<<B_, 512, 0, stream>>>(partial, Wp, bp, probs_out, chosen_out, chosen);
  transpose_cvt2_kernel<<<dim3(256, 1, 2 * E_), 256, 0, stream>>>(W1, W2, w1t, w2t);

  // h = relu(x @ W1[e] + b1[e])  : M=512,K=512,N=2048, bf16 out
  gemm_bt_kernel<512, 2048, true, __bf16>
      <<<dim3(16, 4, 32), 256, 0, stream>>>(xbf, w1t, b1, hbuf, chosen);
  // out = h @ W2[e] + b2[e]      : M=512,K=2048,N=512, f32 out
  gemm_bt_kernel<2048, 512, false, float>
      <<<dim3(4, 4, 32), 256, 0, stream>>>(hbuf, w2t, b2, final_out, chosen);
}